// Round 5
// baseline (498.097 us; speedup 1.0000x reference)
//
#include <hip/hip_runtime.h>
#include <math.h>

// Problem constants (B, N, D) = (256, 128, 128)
#define B_    256
#define N_    128
#define MAXP  30
#define OTHER_ 35      // D - 2*30 - 1 - 32
#define CIN1  131      // real channels into conv1
#define NIDX  381      // 3*(N-1)

// wT layouts (kk-major): row r = kk*CINTOT + c, columns = COUT
#define CINTOT1 160    // conv1 K padded 131 -> 160 (5 stages of 32)
#define CINTOT2 256
#define CINTOT3 128
#define S_IDX  (B_ * NIDX)          // 97536
#define S_W1   (3 * CINTOT1 * 256)  // 122880
#define S_W2   (3 * CINTOT2 * 128)  // 98304
#define S_W3   (3 * CINTOT3 * 64)   // 24576

// ---------------------------------------------------------------------------
// Fused prep: idx convert (wave-uniform int64 detection) + 3 weight
// transposes into kk-major layout wT[kk*CINTOT + c][o], zero-padded rows.
// ---------------------------------------------------------------------------
__global__ __launch_bounds__(256) void prep_kernel(
    const void* __restrict__ rawIdx, int* __restrict__ idx32,
    const float* __restrict__ w1, float* __restrict__ wT1,
    const float* __restrict__ w2, float* __restrict__ wT2,
    const float* __restrict__ w3, float* __restrict__ wT3) {
  const int gid = blockIdx.x * 256 + threadIdx.x;
  if (gid < S_IDX) {
    // int64 LE view is (v,0,v,0,...) with v in [0,128)
    const int* r32 = (const int*)rawIdx;
    const int lane = threadIdx.x & 63;
    const int lo = r32[2 * lane];
    const int hi = r32[2 * lane + 1];
    const bool ok = (hi == 0 && lo >= 0 && lo < N_);
    const bool is64 = __all(ok);
    idx32[gid] = is64 ? (int)((const long long*)rawIdx)[gid] : r32[gid];
  } else if (gid < S_IDX + S_W1) {
    const int l = gid - S_IDX;
    const int o = l & 255, r = l >> 8;          // r in [0,480)
    const int kk = r / CINTOT1, c = r - kk * CINTOT1;
    wT1[l] = (c < CIN1) ? w1[o * 393 + c * 3 + kk] : 0.f;
  } else if (gid < S_IDX + S_W1 + S_W2) {
    const int l = gid - (S_IDX + S_W1);
    const int o = l & 127, r = l >> 7;          // r in [0,768)
    const int kk = r >> 8, c = r & 255;
    wT2[l] = w2[o * 768 + c * 3 + kk];
  } else if (gid < S_IDX + S_W1 + S_W2 + S_W3) {
    const int l = gid - (S_IDX + S_W1 + S_W2);
    const int o = l & 63, r = l >> 6;           // r in [0,384)
    const int kk = r >> 7, c = r & 127;
    wT3[l] = w3[o * 384 + c * 3 + kk];
  }
}

// ---------------------------------------------------------------------------
// Embedding + collate (row stride 160, channels 131..159 zeroed).
// ---------------------------------------------------------------------------
__global__ __launch_bounds__(256) void embed_kernel(
    const float* __restrict__ feature,
    const float* __restrict__ col_embed,   // (200,32)
    const float* __restrict__ op_embed,    // (20,32)
    float* __restrict__ collate) {
  const int tid  = threadIdx.x;
  const int wave = tid >> 6;
  const int lane = tid & 63;
  const int b = blockIdx.x >> 5;
  const int n = ((blockIdx.x & 31) << 2) | wave;

  const float* fb = feature + ((size_t)b * 128) * 128 + n;  // stride 128 over d

  int civ = 0, oiv = 0;
  if (lane < MAXP) civ = (int)fb[(OTHER_ + lane) * 128];
  if (lane >= 32 && lane < 32 + MAXP) oiv = (int)fb[(OTHER_ + MAXP + (lane - 32)) * 128];
  const int L = (int)fb[95 * 128];  // wave-uniform

  const float* tp = (lane < 32) ? col_embed : op_embed;
  const int cl = lane & 31;
  float acc = 0.f;
  for (int i = 0; i < L; ++i) {
    const int cv = __shfl(civ, i);
    const int ov = __shfl(oiv, 32 + i);
    const int row = (lane < 32) ? cv : ov;
    acc += tp[row * 32 + cl];
  }

  float* out = collate + ((size_t)b * 128 + n) * CINTOT1;
  out[35 + lane] = acc;
  if (lane < 35) out[lane] = fb[lane * 128];
  if (lane < 32) out[99 + lane] = fb[(96 + lane) * 128];
  if (lane < 29) out[131 + lane] = 0.f;   // pad channels
}

// ---------------------------------------------------------------------------
// Tree conv v5 (= r3 layout, small LDS, 4 blocks/CU):
// Block = (batch, chunk), 512 threads = 8 waves, LDS ~20 KB.
// chunk -> co = chunk/JCH (oc0 = co*64), cj = chunk%JCH (jbase = cj*128/JCH).
// tx = tid&15 owns 4 consecutive oc (LDS X-reads broadcast across 16 lanes);
// ty = tid>>4 owns JPT consecutive j. K staged in NSTAGE sub-stages of CST=32
// floats (float4, guard-free; input stride divisible by 32). Input norm+leaky
// fused at staging. Stats partials per chunk in f64 (deterministic combine).
// ---------------------------------------------------------------------------
template <int CINSTRIDE, int CST, int CINP, int CINTOT, int COUTtot,
          int OCCH, int JCH, int JPT, bool NORM_IN, int NCH_IN, int NSTAGE,
          int CREAL>
__global__ __launch_bounds__(512, 8) void conv_kernel(
    const float* __restrict__ X,        // (B,128,CINSTRIDE) node-major
    const int* __restrict__ idx,        // (B,381)
    const float* __restrict__ wT,       // (3*CINTOT, COUTtot) kk-major
    const float* __restrict__ bias,     // (COUTtot)
    const double* __restrict__ statsIn, // (B, NCH_IN, 2) partials
    float* __restrict__ Y,              // (B,128,COUTtot) node-major
    double* __restrict__ statsOut) {    // (B, OCCH*JCH, 2) partials
  __shared__ float xs[128 * CINP];
  __shared__ int nb_s[NIDX];
  __shared__ double red[16];

  const int b = blockIdx.x;
  const int chunk = blockIdx.y;
  const int co = chunk / JCH;
  const int cj = chunk - co * JCH;
  const int oc0 = co * 64;
  const int jbase = cj * (128 / JCH);
  const int tid = threadIdx.x;

  float mean = 0.f, inv = 1.f;
  if (NORM_IN) {
    double S = 0.0, Q = 0.0;
#pragma unroll
    for (int i = 0; i < NCH_IN; ++i) {
      S += statsIn[(b * NCH_IN + i) * 2];
      Q += statsIn[(b * NCH_IN + i) * 2 + 1];
    }
    const double cnt = (double)CREAL * 128.0;
    const double m = S / cnt;
    double var = (Q - S * S / cnt) / (cnt - 1.0);
    if (var < 0.0) var = 0.0;
    mean = (float)m;
    inv = (float)(1.0 / (sqrt(var) + 1e-5));
  }

  const int tx = tid & 15;   // 4 consecutive oc -> 64 oc per chunk
  const int ty = tid >> 4;   // 32 groups of JPT consecutive j

  float acc[4][JPT];
#pragma unroll
  for (int i = 0; i < 4; ++i)
#pragma unroll
    for (int jj = 0; jj < JPT; ++jj) acc[i][jj] = 0.f;

  const float* __restrict__ Xb = X + (size_t)b * (128 * CINSTRIDE);
  constexpr int F4PR = CST / 4;          // float4 per row per stage
  constexpr int NF4 = 128 * F4PR;

  int rowoff[JPT][3];
  double s_sum = 0.0, s_sq = 0.0;

  for (int s = 0; s < NSTAGE; ++s) {
    if (s > 0) __syncthreads();  // protect prior-stage reads
    for (int t = tid; t < NF4; t += 512) {
      const int n = t / F4PR;
      const int c4 = (t - n * F4PR) * 4;
      float4 v = *reinterpret_cast<const float4*>(&Xb[n * CINSTRIDE + s * CST + c4]);
      if (NORM_IN) {
        v.x = (v.x - mean) * inv; v.x = (v.x > 0.f) ? v.x : 0.01f * v.x;
        v.y = (v.y - mean) * inv; v.y = (v.y > 0.f) ? v.y : 0.01f * v.y;
        v.z = (v.z - mean) * inv; v.z = (v.z > 0.f) ? v.z : 0.01f * v.z;
        v.w = (v.w - mean) * inv; v.w = (v.w > 0.f) ? v.w : 0.01f * v.w;
      }
      *reinterpret_cast<float4*>(&xs[n * CINP + c4]) = v;
    }
    if (s == 0 && tid < NIDX) nb_s[tid] = idx[b * NIDX + tid];
    __syncthreads();

    if (s == 0) {
#pragma unroll
      for (int jj = 0; jj < JPT; ++jj) {
        const int j = jbase + ty * JPT + jj;
#pragma unroll
        for (int kk = 0; kk < 3; ++kk) {
          const int nbv = (j > 0) ? nb_s[(j - 1) * 3 + kk] : 0;
          rowoff[jj][kk] = nbv * CINP;
        }
      }
    }

    const float* wp0 = wT + ((size_t)(0 * CINTOT + s * CST)) * COUTtot + oc0 + tx * 4;
    const float* wp1 = wT + ((size_t)(1 * CINTOT + s * CST)) * COUTtot + oc0 + tx * 4;
    const float* wp2 = wT + ((size_t)(2 * CINTOT + s * CST)) * COUTtot + oc0 + tx * 4;

    for (int c = 0; c < CST; c += 4) {
#pragma unroll
      for (int kk = 0; kk < 3; ++kk) {
        const float* wr = (kk == 0 ? wp0 : kk == 1 ? wp1 : wp2) + c * COUTtot;
        float xq[JPT][4];
#pragma unroll
        for (int jj = 0; jj < JPT; ++jj)
          *reinterpret_cast<float4*>(xq[jj]) =
              *reinterpret_cast<const float4*>(&xs[rowoff[jj][kk] + c]);
#pragma unroll
        for (int cc = 0; cc < 4; ++cc) {
          const float4 w4 = *reinterpret_cast<const float4*>(wr + cc * COUTtot);
#pragma unroll
          for (int jj = 0; jj < JPT; ++jj) {
            const float xv = xq[jj][cc];
            acc[0][jj] = fmaf(w4.x, xv, acc[0][jj]);
            acc[1][jj] = fmaf(w4.y, xv, acc[1][jj]);
            acc[2][jj] = fmaf(w4.z, xv, acc[2][jj]);
            acc[3][jj] = fmaf(w4.w, xv, acc[3][jj]);
          }
        }
      }
    }
  }

  // ---- epilogue: bias, zero column, stats partial, store ----
  const float4 b4 = *reinterpret_cast<const float4*>(bias + oc0 + tx * 4);
#pragma unroll
  for (int jj = 0; jj < JPT; ++jj) {
    const int j = jbase + ty * JPT + jj;
    float4 o4;
    if (j > 0) {
      o4.x = acc[0][jj] + b4.x;
      o4.y = acc[1][jj] + b4.y;
      o4.z = acc[2][jj] + b4.z;
      o4.w = acc[3][jj] + b4.w;
    } else {
      o4.x = 0.f; o4.y = 0.f; o4.z = 0.f; o4.w = 0.f;
    }
    s_sum += (double)o4.x + (double)o4.y + (double)o4.z + (double)o4.w;
    s_sq  += (double)o4.x * o4.x + (double)o4.y * o4.y +
             (double)o4.z * o4.z + (double)o4.w * o4.w;
    *reinterpret_cast<float4*>(Y + ((size_t)b * 128 + j) * COUTtot + oc0 + tx * 4) = o4;
  }

#pragma unroll
  for (int o = 32; o > 0; o >>= 1) {
    s_sum += __shfl_down(s_sum, o, 64);
    s_sq  += __shfl_down(s_sq, o, 64);
  }
  const int w = tid >> 6;
  if ((tid & 63) == 0) { red[w * 2] = s_sum; red[w * 2 + 1] = s_sq; }
  __syncthreads();
  if (tid == 0) {
    double S = 0.0, Q = 0.0;
#pragma unroll
    for (int i = 0; i < 8; ++i) { S += red[i * 2]; Q += red[i * 2 + 1]; }
    statsOut[(b * (OCCH * JCH) + chunk) * 2] = S;
    statsOut[(b * (OCCH * JCH) + chunk) * 2 + 1] = Q;
  }
}

// ---------------------------------------------------------------------------
// Final: combine conv3 stats partials (4), normalize, maxpool, 2-layer MLP.
// ---------------------------------------------------------------------------
__global__ __launch_bounds__(64) void final_kernel(
    const float* __restrict__ Y3,      // (B,128,64)
    const double* __restrict__ st,     // (B,4,2) partials
    const float* __restrict__ fw1,     // (32,64)
    const float* __restrict__ fb1,     // (32)
    const float* __restrict__ fw2,     // (1,32)
    const float* __restrict__ fb2,     // (1)
    float* __restrict__ out) {
  const int b = blockIdx.x;
  const int lane = threadIdx.x;

  double S = 0.0, Q = 0.0;
#pragma unroll
  for (int i = 0; i < 4; ++i) {
    S += st[(b * 4 + i) * 2];
    Q += st[(b * 4 + i) * 2 + 1];
  }
  const double cnt = 64.0 * 128.0;
  const double m = S / cnt;
  double var = (Q - S * S / cnt) / (cnt - 1.0);
  if (var < 0.0) var = 0.0;
  const float mean = (float)m;
  const float inv = (float)(1.0 / (sqrt(var) + 1e-5));

  const float* Yb = Y3 + (size_t)b * 128 * 64;
  float mx = -3.4e38f;
  for (int n = 0; n < 128; ++n) {
    const float v = (Yb[n * 64 + lane] - mean) * inv;
    mx = fmaxf(mx, v);
  }
  __shared__ float pooled[64];
  __shared__ float hs[32];
  pooled[lane] = mx;
  __syncthreads();
  if (lane < 32) {
    float a = fb1[lane];
    for (int c = 0; c < 64; ++c) a = fmaf(pooled[c], fw1[lane * 64 + c], a);
    hs[lane] = fmaxf(a, 0.f);
  }
  __syncthreads();
  if (lane == 0) {
    float s = fb2[0];
    for (int t = 0; t < 32; ++t) s = fmaf(hs[t], fw2[t], s);
    out[b] = s;
  }
}

// ---------------------------------------------------------------------------
extern "C" void kernel_launch(void* const* d_in, const int* in_sizes, int n_in,
                              void* d_out, int out_size, void* d_ws, size_t ws_size,
                              hipStream_t stream) {
  const float* feature   = (const float*)d_in[0];
  const void*  indexes   = d_in[1];
  const float* col_embed = (const float*)d_in[2];
  const float* op_embed  = (const float*)d_in[3];
  const float* w1  = (const float*)d_in[4];
  const float* b1  = (const float*)d_in[5];
  const float* w2  = (const float*)d_in[6];
  const float* b2  = (const float*)d_in[7];
  const float* w3  = (const float*)d_in[8];
  const float* b3  = (const float*)d_in[9];
  const float* fw1 = (const float*)d_in[10];
  const float* fb1 = (const float*)d_in[11];
  const float* fw2 = (const float*)d_in[12];
  const float* fb2 = (const float*)d_in[13];
  float* out = (float*)d_out;

  char* ws = (char*)d_ws;
  size_t off = 0;
  auto carve = [&](size_t bytes) -> char* {
    off = (off + 255) & ~(size_t)255;
    char* p = ws + off;
    off += bytes;
    return p;
  };
  int*    idx32   = (int*)carve((size_t)S_IDX * sizeof(int));
  float*  wT1     = (float*)carve((size_t)S_W1 * sizeof(float));
  float*  wT2     = (float*)carve((size_t)S_W2 * sizeof(float));
  float*  wT3     = (float*)carve((size_t)S_W3 * sizeof(float));
  float*  collate = (float*)carve((size_t)B_ * 128 * CINTOT1 * sizeof(float));
  float*  Y1      = (float*)carve((size_t)B_ * 128 * 256 * sizeof(float));
  float*  Y2      = (float*)carve((size_t)B_ * 128 * 128 * sizeof(float));
  float*  Y3      = (float*)carve((size_t)B_ * 128 * 64 * sizeof(float));
  double* st1     = (double*)carve((size_t)B_ * 4 * 2 * sizeof(double));
  double* st2     = (double*)carve((size_t)B_ * 4 * 2 * sizeof(double));
  double* st3     = (double*)carve((size_t)B_ * 4 * 2 * sizeof(double));
  (void)ws_size; (void)in_sizes; (void)n_in; (void)out_size;

  constexpr int PREP_TOTAL = S_IDX + S_W1 + S_W2 + S_W3;
  hipLaunchKernelGGL(prep_kernel, dim3((PREP_TOTAL + 255) / 256), dim3(256), 0, stream,
                     indexes, idx32, w1, wT1, w2, wT2, w3, wT3);
  hipLaunchKernelGGL(embed_kernel, dim3(B_ * 32), dim3(256), 0, stream,
                     feature, col_embed, op_embed, collate);
  // conv1: stride 160, 5 stages of 32 (CINP 36), 4 oc-chunks, JPT 4
  hipLaunchKernelGGL((conv_kernel<160, 32, 36, CINTOT1, 256, 4, 1, 4, false, 1, 5, CIN1>),
                     dim3(B_, 4), dim3(512), 0, stream,
                     collate, idx32, wT1, b1, (const double*)nullptr, Y1, st1);
  // conv2: stride 256, 8 stages of 32, 2 oc x 2 j chunks, JPT 2
  hipLaunchKernelGGL((conv_kernel<256, 32, 36, CINTOT2, 128, 2, 2, 2, true, 4, 8, 256>),
                     dim3(B_, 4), dim3(512), 0, stream,
                     Y1, idx32, wT2, b2, st1, Y2, st2);
  // conv3: stride 128, 4 stages of 32, 1 oc x 4 j chunks, JPT 1
  hipLaunchKernelGGL((conv_kernel<128, 32, 36, CINTOT3, 64, 1, 4, 1, true, 4, 4, 128>),
                     dim3(B_, 4), dim3(512), 0, stream,
                     Y2, idx32, wT3, b3, st2, Y3, st3);
  hipLaunchKernelGGL(final_kernel, dim3(B_), dim3(64), 0, stream,
                     Y3, st3, fw1, fb1, fw2, fb2, out);
}

// Round 6
// 132.025 us; speedup vs baseline: 3.7727x; 3.7727x over previous
//
#include <hip/hip_runtime.h>
#include <math.h>

// Problem constants (B, N, D) = (256, 128, 128)
#define B_    256
#define N_    128
#define MAXP  30
#define OTHER_ 35
#define CIN1  131      // real channels into conv1
#define NIDX  381      // 3*(N-1)

// conv K-geometry: KPAD per kk-region, 3 regions; fragment k-steps of 32
#define KPAD1 160
#define KPAD2 256
#define KPAD3 128
// weight-pack element counts: KSTEPS*4wo*SUB*512
#define S_IDX (B_ * NIDX)
#define S_P1  (15 * 4 * 4 * 512)   // 122880
#define S_P2  (24 * 4 * 2 * 512)   // 98304
#define S_P3  (12 * 4 * 1 * 512)   // 24576

typedef short short8 __attribute__((ext_vector_type(8)));
typedef float f32x4 __attribute__((ext_vector_type(4)));

// RNE split of f32 into hi/lo bf16 (bit patterns as short)
__device__ inline void split1(float v, short& h, short& l) {
  unsigned u = __float_as_uint(v);
  unsigned hb = (u + 0x7fffu + ((u >> 16) & 1u)) >> 16;
  float fh = __uint_as_float(hb << 16);
  float r = v - fh;
  unsigned u2 = __float_as_uint(r);
  unsigned lb = (u2 + 0x7fffu + ((u2 >> 16) & 1u)) >> 16;
  h = (short)hb;
  l = (short)lb;
}

// ---------------------------------------------------------------------------
// Weight pack: element l -> fragment layout [gks][wo][s][lane][e], value
// w[oc][ch][kk] split into hi/lo bf16. Map: oc=(wo*SUB+s)*16+(lane&15),
// ctot=gks*32+((lane>>4)&3)*8+e, kk=ctot/KPAD, ch=ctot%KPAD (0 if ch>=KREAL).
// ---------------------------------------------------------------------------
template <int KREAL, int KPAD, int SUB>
__device__ inline void packw(int l, const float* __restrict__ w,
                             short* __restrict__ oh, short* __restrict__ ol) {
  const int e = l & 7;
  const int lane = (l >> 3) & 63;
  const int x = l >> 9;
  const int s = x % SUB;
  const int y = x / SUB;
  const int wo = y & 3;
  const int gks = y >> 2;
  const int oc = (wo * SUB + s) * 16 + (lane & 15);
  const int ctot = gks * 32 + ((lane >> 4) & 3) * 8 + e;
  const int kk = ctot / KPAD;
  const int ch = ctot - kk * KPAD;
  const float v = (ch < KREAL) ? w[(oc * KREAL + ch) * 3 + kk] : 0.f;
  short h, lo;
  split1(v, h, lo);
  oh[l] = h;
  ol[l] = lo;
}

__global__ __launch_bounds__(256) void prep_kernel(
    const void* __restrict__ rawIdx, int* __restrict__ idx32,
    const float* __restrict__ w1, short* __restrict__ w1h, short* __restrict__ w1l,
    const float* __restrict__ w2, short* __restrict__ w2h, short* __restrict__ w2l,
    const float* __restrict__ w3, short* __restrict__ w3h, short* __restrict__ w3l) {
  const int gid = blockIdx.x * 256 + threadIdx.x;
  if (gid < S_IDX) {
    // int64 LE view is (v,0,v,0,...) with v in [0,128)
    const int* r32 = (const int*)rawIdx;
    const int lane = threadIdx.x & 63;
    const int lo = r32[2 * lane];
    const int hi = r32[2 * lane + 1];
    const bool ok = (hi == 0 && lo >= 0 && lo < N_);
    const bool is64 = __all(ok);
    idx32[gid] = is64 ? (int)((const long long*)rawIdx)[gid] : r32[gid];
  } else if (gid < S_IDX + S_P1) {
    packw<131, KPAD1, 4>(gid - S_IDX, w1, w1h, w1l);
  } else if (gid < S_IDX + S_P1 + S_P2) {
    packw<256, KPAD2, 2>(gid - (S_IDX + S_P1), w2, w2h, w2l);
  } else if (gid < S_IDX + S_P1 + S_P2 + S_P3) {
    packw<128, KPAD3, 1>(gid - (S_IDX + S_P1 + S_P2), w3, w3h, w3l);
  }
}

// ---------------------------------------------------------------------------
// Embedding + collate (row stride 160, channels 131..159 zeroed).
// ---------------------------------------------------------------------------
__global__ __launch_bounds__(256) void embed_kernel(
    const float* __restrict__ feature,
    const float* __restrict__ col_embed,   // (200,32)
    const float* __restrict__ op_embed,    // (20,32)
    float* __restrict__ collate) {
  const int tid  = threadIdx.x;
  const int wave = tid >> 6;
  const int lane = tid & 63;
  const int b = blockIdx.x >> 5;
  const int n = ((blockIdx.x & 31) << 2) | wave;

  const float* fb = feature + ((size_t)b * 128) * 128 + n;  // stride 128 over d

  int civ = 0, oiv = 0;
  if (lane < MAXP) civ = (int)fb[(OTHER_ + lane) * 128];
  if (lane >= 32 && lane < 32 + MAXP) oiv = (int)fb[(OTHER_ + MAXP + (lane - 32)) * 128];
  const int L = (int)fb[95 * 128];  // wave-uniform

  const float* tp = (lane < 32) ? col_embed : op_embed;
  const int cl = lane & 31;
  float acc = 0.f;
  for (int i = 0; i < L; ++i) {
    const int cv = __shfl(civ, i);
    const int ov = __shfl(oiv, 32 + i);
    const int row = (lane < 32) ? cv : ov;
    acc += tp[row * 32 + cl];
  }

  float* out = collate + ((size_t)b * 128 + n) * KPAD1;
  out[35 + lane] = acc;
  if (lane < 35) out[lane] = fb[lane * 128];
  if (lane < 32) out[99 + lane] = fb[(96 + lane) * 128];
  if (lane < 29) out[131 + lane] = 0.f;   // pad channels
}

// ---------------------------------------------------------------------------
// MFMA tree conv: block = one batch (grid 256), 512 threads = 8 waves
// arranged (wj 0..1) x (wo 0..3). Wave computes j in [wj*64, wj*64+64)
// (4 jt tiles of 16) x oc in [(wo*SUB)*16, +SUB*16).
// X staged once in LDS as bf16 hi/lo, XOR-swizzled (elem ^= (row&7)<<3).
// A row j, channel c: kk = c/KPAD, ch = c%KPAD -> X[nb(j,kk)][ch].
// Weights pre-packed in fragment order (coalesced 16B/lane loads from L2).
// acc[jt][s] f32x4; 3 MFMAs per tile-kstep: xh*wh + xl*wh + xh*wl.
// Epilogue: bias, zero col j=0, f64 stats partial {S,Q} -> statsOut[b].
// ---------------------------------------------------------------------------
template <int KPAD, int KREAL, int SUB, bool NORM_IN>
__global__ __launch_bounds__(512, 2) void convm_kernel(
    const float* __restrict__ X,        // (B,128,KPAD) node-major f32
    const int* __restrict__ idx,        // (B,381)
    const short* __restrict__ wH, const short* __restrict__ wL,
    const float* __restrict__ bias,     // (COUT)
    const double* __restrict__ statsIn, // (B,2) {S,Q} or null
    float* __restrict__ Y,              // (B,128,COUT)
    double* __restrict__ statsOut) {    // (B,2)
  constexpr int KPS = KPAD / 32;        // ksteps per kk region
  constexpr int COUT = SUB * 64;
  constexpr int JT = 4;
  constexpr int PK = KPAD / 8;          // 8-elem packs per row

  __shared__ short xhi[128 * KPAD];
  __shared__ short xlo[128 * KPAD];
  __shared__ int nb_s[NIDX];
  __shared__ double red[16];

  const int b = blockIdx.x;
  const int tid = threadIdx.x;
  const int lane = tid & 63;
  const int w = tid >> 6;
  const int wj = w >> 2;           // 0..1
  const int wo = w & 3;            // 0..3
  const int grp = (lane >> 4) & 3;

  float mean = 0.f, inv = 1.f;
  if (NORM_IN) {
    const double S = statsIn[b * 2];
    const double Q = statsIn[b * 2 + 1];
    const double cnt = (double)KPAD * 128.0;
    const double m = S / cnt;
    double var = (Q - S * S / cnt) / (cnt - 1.0);
    if (var < 0.0) var = 0.0;
    mean = (float)m;
    inv = (float)(1.0 / (sqrt(var) + 1e-5));
  }

  // ---- stage X -> LDS bf16 hi/lo, swizzled ----
  const float* __restrict__ Xb = X + (size_t)b * (128 * KPAD);
#pragma unroll
  for (int it = 0; it < (128 * PK) / 512; ++it) {
    const int t = it * 512 + tid;
    const int n = t / PK;
    const int ch0 = (t - n * PK) * 8;
    const float4 a0 = *reinterpret_cast<const float4*>(&Xb[n * KPAD + ch0]);
    const float4 a1 = *reinterpret_cast<const float4*>(&Xb[n * KPAD + ch0 + 4]);
    float vv[8] = {a0.x, a0.y, a0.z, a0.w, a1.x, a1.y, a1.z, a1.w};
    short8 h8, l8;
#pragma unroll
    for (int i = 0; i < 8; ++i) {
      float v = vv[i];
      if (NORM_IN) {
        v = (v - mean) * inv;
        v = (v > 0.f) ? v : 0.01f * v;
      }
      short h, l;
      split1(v, h, l);
      h8[i] = h;
      l8[i] = l;
    }
    const int ei = (n * KPAD + ch0) ^ ((n & 7) << 3);
    *reinterpret_cast<short8*>(&xhi[ei]) = h8;
    *reinterpret_cast<short8*>(&xlo[ei]) = l8;
  }
  if (tid < NIDX) nb_s[tid] = idx[b * NIDX + tid];
  __syncthreads();

  // ---- per-lane gather rows for A fragments ----
  int nbr[JT][3];
#pragma unroll
  for (int jt = 0; jt < JT; ++jt) {
    const int j = wj * 64 + jt * 16 + (lane & 15);
#pragma unroll
    for (int kk = 0; kk < 3; ++kk)
      nbr[jt][kk] = (j > 0) ? nb_s[(j - 1) * 3 + kk] : 0;
  }

  f32x4 acc[JT][SUB];
#pragma unroll
  for (int jt = 0; jt < JT; ++jt)
#pragma unroll
    for (int s = 0; s < SUB; ++s) {
      acc[jt][s][0] = 0.f; acc[jt][s][1] = 0.f;
      acc[jt][s][2] = 0.f; acc[jt][s][3] = 0.f;
    }

  const short8* __restrict__ wH8 = (const short8*)wH;
  const short8* __restrict__ wL8 = (const short8*)wL;

#pragma unroll
  for (int kk = 0; kk < 3; ++kk) {
    for (int ks = 0; ks < KPS; ++ks) {
      const int gks = kk * KPS + ks;
      short8 bh[SUB], bl[SUB];
#pragma unroll
      for (int s = 0; s < SUB; ++s) {
        const int wi = ((gks * 4 + wo) * SUB + s) * 64 + lane;
        bh[s] = wH8[wi];
        bl[s] = wL8[wi];
      }
      const int ch0 = ks * 32 + grp * 8;
#pragma unroll
      for (int jt = 0; jt < JT; ++jt) {
        const int rb = nbr[jt][kk];
        const int ei = (rb * KPAD + ch0) ^ ((rb & 7) << 3);
        const short8 ah = *reinterpret_cast<const short8*>(&xhi[ei]);
        const short8 al = *reinterpret_cast<const short8*>(&xlo[ei]);
#pragma unroll
        for (int s = 0; s < SUB; ++s) {
          acc[jt][s] = __builtin_amdgcn_mfma_f32_16x16x32_bf16(ah, bh[s], acc[jt][s], 0, 0, 0);
          acc[jt][s] = __builtin_amdgcn_mfma_f32_16x16x32_bf16(al, bh[s], acc[jt][s], 0, 0, 0);
          acc[jt][s] = __builtin_amdgcn_mfma_f32_16x16x32_bf16(ah, bl[s], acc[jt][s], 0, 0, 0);
        }
      }
    }
  }

  // ---- epilogue: bias, zero col, store, f64 stats ----
  double s_sum = 0.0, s_sq = 0.0;
#pragma unroll
  for (int s = 0; s < SUB; ++s) {
    const int oc = (wo * SUB + s) * 16 + (lane & 15);
    const float bv = bias[oc];
#pragma unroll
    for (int jt = 0; jt < JT; ++jt) {
#pragma unroll
      for (int r = 0; r < 4; ++r) {
        const int j = wj * 64 + jt * 16 + grp * 4 + r;
        const float val = (j > 0) ? acc[jt][s][r] + bv : 0.f;
        Y[((size_t)b * 128 + j) * COUT + oc] = val;
        s_sum += (double)val;
        s_sq += (double)val * (double)val;
      }
    }
  }

#pragma unroll
  for (int o = 32; o > 0; o >>= 1) {
    s_sum += __shfl_down(s_sum, o, 64);
    s_sq  += __shfl_down(s_sq, o, 64);
  }
  if (lane == 0) { red[w * 2] = s_sum; red[w * 2 + 1] = s_sq; }
  __syncthreads();
  if (tid == 0) {
    double S = 0.0, Q = 0.0;
#pragma unroll
    for (int i = 0; i < 8; ++i) { S += red[i * 2]; Q += red[i * 2 + 1]; }
    statsOut[b * 2] = S;
    statsOut[b * 2 + 1] = Q;
  }
}

// ---------------------------------------------------------------------------
// Final: combine conv3 stats, normalize, maxpool, 2-layer MLP.
// ---------------------------------------------------------------------------
__global__ __launch_bounds__(64) void final_kernel(
    const float* __restrict__ Y3,      // (B,128,64)
    const double* __restrict__ st,     // (B,2)
    const float* __restrict__ fw1,     // (32,64)
    const float* __restrict__ fb1,     // (32)
    const float* __restrict__ fw2,     // (1,32)
    const float* __restrict__ fb2,     // (1)
    float* __restrict__ out) {
  const int b = blockIdx.x;
  const int lane = threadIdx.x;

  const double S = st[b * 2];
  const double Q = st[b * 2 + 1];
  const double cnt = 64.0 * 128.0;
  const double m = S / cnt;
  double var = (Q - S * S / cnt) / (cnt - 1.0);
  if (var < 0.0) var = 0.0;
  const float mean = (float)m;
  const float inv = (float)(1.0 / (sqrt(var) + 1e-5));

  const float* Yb = Y3 + (size_t)b * 128 * 64;
  float mx = -3.4e38f;
  for (int n = 0; n < 128; ++n) {
    const float v = (Yb[n * 64 + lane] - mean) * inv;
    mx = fmaxf(mx, v);
  }
  __shared__ float pooled[64];
  __shared__ float hs[32];
  pooled[lane] = mx;
  __syncthreads();
  if (lane < 32) {
    float a = fb1[lane];
    for (int c = 0; c < 64; ++c) a = fmaf(pooled[c], fw1[lane * 64 + c], a);
    hs[lane] = fmaxf(a, 0.f);
  }
  __syncthreads();
  if (lane == 0) {
    float s = fb2[0];
    for (int t = 0; t < 32; ++t) s = fmaf(hs[t], fw2[t], s);
    out[b] = s;
  }
}

// ---------------------------------------------------------------------------
extern "C" void kernel_launch(void* const* d_in, const int* in_sizes, int n_in,
                              void* d_out, int out_size, void* d_ws, size_t ws_size,
                              hipStream_t stream) {
  const float* feature   = (const float*)d_in[0];
  const void*  indexes   = d_in[1];
  const float* col_embed = (const float*)d_in[2];
  const float* op_embed  = (const float*)d_in[3];
  const float* w1  = (const float*)d_in[4];
  const float* b1  = (const float*)d_in[5];
  const float* w2  = (const float*)d_in[6];
  const float* b2  = (const float*)d_in[7];
  const float* w3  = (const float*)d_in[8];
  const float* b3  = (const float*)d_in[9];
  const float* fw1 = (const float*)d_in[10];
  const float* fb1 = (const float*)d_in[11];
  const float* fw2 = (const float*)d_in[12];
  const float* fb2 = (const float*)d_in[13];
  float* out = (float*)d_out;

  char* ws = (char*)d_ws;
  size_t off = 0;
  auto carve = [&](size_t bytes) -> char* {
    off = (off + 255) & ~(size_t)255;
    char* p = ws + off;
    off += bytes;
    return p;
  };
  int*    idx32   = (int*)carve((size_t)S_IDX * sizeof(int));
  short*  w1h     = (short*)carve((size_t)S_P1 * sizeof(short));
  short*  w1l     = (short*)carve((size_t)S_P1 * sizeof(short));
  short*  w2h     = (short*)carve((size_t)S_P2 * sizeof(short));
  short*  w2l     = (short*)carve((size_t)S_P2 * sizeof(short));
  short*  w3h     = (short*)carve((size_t)S_P3 * sizeof(short));
  short*  w3l     = (short*)carve((size_t)S_P3 * sizeof(short));
  float*  collate = (float*)carve((size_t)B_ * 128 * KPAD1 * sizeof(float));
  float*  Y1      = (float*)carve((size_t)B_ * 128 * 256 * sizeof(float));
  float*  Y2      = (float*)carve((size_t)B_ * 128 * 128 * sizeof(float));
  float*  Y3      = (float*)carve((size_t)B_ * 128 * 64 * sizeof(float));
  double* st1     = (double*)carve((size_t)B_ * 2 * sizeof(double));
  double* st2     = (double*)carve((size_t)B_ * 2 * sizeof(double));
  double* st3     = (double*)carve((size_t)B_ * 2 * sizeof(double));
  (void)ws_size; (void)in_sizes; (void)n_in; (void)out_size;

  constexpr int PREP_TOTAL = S_IDX + S_P1 + S_P2 + S_P3;
  hipLaunchKernelGGL(prep_kernel, dim3((PREP_TOTAL + 255) / 256), dim3(256), 0, stream,
                     indexes, idx32, w1, w1h, w1l, w2, w2h, w2l, w3, w3h, w3l);
  hipLaunchKernelGGL(embed_kernel, dim3(B_ * 32), dim3(256), 0, stream,
                     feature, col_embed, op_embed, collate);
  hipLaunchKernelGGL((convm_kernel<KPAD1, CIN1, 4, false>), dim3(B_), dim3(512), 0, stream,
                     collate, idx32, w1h, w1l, b1, (const double*)nullptr, Y1, st1);
  hipLaunchKernelGGL((convm_kernel<KPAD2, 256, 2, true>), dim3(B_), dim3(512), 0, stream,
                     Y1, idx32, w2h, w2l, b2, st1, Y2, st2);
  hipLaunchKernelGGL((convm_kernel<KPAD3, 128, 1, true>), dim3(B_), dim3(512), 0, stream,
                     Y2, idx32, w3h, w3l, b3, st2, Y3, st3);
  hipLaunchKernelGGL(final_kernel, dim3(B_), dim3(64), 0, stream,
                     Y3, st3, fw1, fb1, fw2, fb2, out);
}